// Round 5
// baseline (1575.037 us; speedup 1.0000x reference)
//
// Round 5 resubmission: rounds 2-4 never reached hardware (GPUAcquisitionTimeout
// at the broker — infra capacity, zero information about this source).
// Baseline logic intentionally unchanged; first successful bench must validate
// structure (layouts/attention/ws) before any numerics change (bf16/MFMA) so
// failures stay single-unknown.
#include <hip/hip_runtime.h>
#include <math.h>

namespace {

constexpr int S_LEN = 2048;
constexpr int NH    = 16;
constexpr int DH    = 64;
constexpr int DE    = 1024;
constexpr float ATT_SCALE = 0.125f;  // 64^-0.5

// C[m,n] = sum_k A[m,k] * W[n,k]   (torch Linear: y = x @ W.T)
// mode 0: C[m*N+n]   mode 1: scatter to [B, H, S, Dh] (m = b*S+s, n = h*DH+dh)
__global__ __launch_bounds__(256) void gemm_nt_kernel(
    const float* __restrict__ A, const float* __restrict__ W,
    float* __restrict__ C, int M, int N, int K, int mode)
{
  constexpr int BK = 16;
  constexpr int P  = 68;          // pad: keeps ds_write 2-way max, reads 16B-aligned
  __shared__ float As[BK][P];     // stored k-major: As[k][row]
  __shared__ float Bs[BK][P];

  const int m0  = blockIdx.x * 64;
  const int n0  = blockIdx.y * 64;
  const int tid = threadIdx.x;
  const int ty  = tid >> 4;       // 0..15 -> 4 output rows
  const int tx  = tid & 15;       // 0..15 -> 4 output cols
  const int lrow = tid >> 2;      // 0..63  (staging row)
  const int lk   = (tid & 3) << 2;// 0,4,8,12 (staging k offset)

  float c[4][4] = {};

  const float* Arow = A + (size_t)(m0 + lrow) * K + lk;
  const float* Wrow = W + (size_t)(n0 + lrow) * K + lk;

  for (int k0 = 0; k0 < K; k0 += BK) {
    const float4 av = *reinterpret_cast<const float4*>(Arow + k0);
    const float4 wv = *reinterpret_cast<const float4*>(Wrow + k0);
    __syncthreads();
    As[lk+0][lrow] = av.x; As[lk+1][lrow] = av.y;
    As[lk+2][lrow] = av.z; As[lk+3][lrow] = av.w;
    Bs[lk+0][lrow] = wv.x; Bs[lk+1][lrow] = wv.y;
    Bs[lk+2][lrow] = wv.z; Bs[lk+3][lrow] = wv.w;
    __syncthreads();
#pragma unroll
    for (int k = 0; k < BK; ++k) {
      const float4 a = *reinterpret_cast<const float4*>(&As[k][ty << 2]);
      const float4 b = *reinterpret_cast<const float4*>(&Bs[k][tx << 2]);
      c[0][0] = fmaf(a.x, b.x, c[0][0]); c[0][1] = fmaf(a.x, b.y, c[0][1]);
      c[0][2] = fmaf(a.x, b.z, c[0][2]); c[0][3] = fmaf(a.x, b.w, c[0][3]);
      c[1][0] = fmaf(a.y, b.x, c[1][0]); c[1][1] = fmaf(a.y, b.y, c[1][1]);
      c[1][2] = fmaf(a.y, b.z, c[1][2]); c[1][3] = fmaf(a.y, b.w, c[1][3]);
      c[2][0] = fmaf(a.z, b.x, c[2][0]); c[2][1] = fmaf(a.z, b.y, c[2][1]);
      c[2][2] = fmaf(a.z, b.z, c[2][2]); c[2][3] = fmaf(a.z, b.w, c[2][3]);
      c[3][0] = fmaf(a.w, b.x, c[3][0]); c[3][1] = fmaf(a.w, b.y, c[3][1]);
      c[3][2] = fmaf(a.w, b.z, c[3][2]); c[3][3] = fmaf(a.w, b.w, c[3][3]);
    }
  }

#pragma unroll
  for (int i = 0; i < 4; ++i) {
    const int row = m0 + (ty << 2) + i;
    const int col = n0 + (tx << 2);
    const float4 v = make_float4(c[i][0], c[i][1], c[i][2], c[i][3]);
    if (mode == 0) {
      *reinterpret_cast<float4*>(&C[(size_t)row * N + col]) = v;
    } else {
      const int b  = row >> 11;            // row / S_LEN
      const int sq = row & (S_LEN - 1);
      const int h  = col >> 6;             // col / DH
      const int dh = col & (DH - 1);
      *reinterpret_cast<float4*>(
          &C[(((size_t)(b * NH + h)) * S_LEN + sq) * DH + dh]) = v;
    }
  }
}

// Q,K,V in [B,H,S,Dh]; O written as [B,S,DE] (head-concat) for the out-proj GEMM.
// One thread per query row; K/V 64-row tiles staged in LDS (broadcast reads).
__global__ __launch_bounds__(256) void attn_kernel(
    const float* __restrict__ Qp, const float* __restrict__ Kp,
    const float* __restrict__ Vp, float* __restrict__ Op)
{
  __shared__ float Ks[64][DH];
  __shared__ float Vs[64][DH];

  const int bh    = blockIdx.x;               // b*NH + h
  const int qbase = blockIdx.y * 256;
  const int row   = qbase + (int)threadIdx.x; // query index in sequence
  const size_t base = (size_t)bh * S_LEN * DH;

  float q[DH];
#pragma unroll
  for (int d4 = 0; d4 < 16; ++d4) {
    const float4 v = *reinterpret_cast<const float4*>(
        &Qp[base + (size_t)row * DH + (d4 << 2)]);
    q[(d4<<2)+0] = v.x; q[(d4<<2)+1] = v.y;
    q[(d4<<2)+2] = v.z; q[(d4<<2)+3] = v.w;
  }

  float o[DH] = {0.f};
  float m = -INFINITY, l = 0.f;

  const int ntiles = (qbase >> 6) + 4;   // covers causal range of block's rows
  for (int t = 0; t < ntiles; ++t) {
    const int k0 = t << 6;
    __syncthreads();
    {
      const float4* Kg = reinterpret_cast<const float4*>(Kp + base + (size_t)k0 * DH);
      const float4* Vg = reinterpret_cast<const float4*>(Vp + base + (size_t)k0 * DH);
      float4* Ks4 = reinterpret_cast<float4*>(&Ks[0][0]);
      float4* Vs4 = reinterpret_cast<float4*>(&Vs[0][0]);
#pragma unroll
      for (int i = 0; i < 4; ++i) {
        const int idx = (int)threadIdx.x + i * 256;  // 0..1023 float4s
        Ks4[idx] = Kg[idx];
        Vs4[idx] = Vg[idx];
      }
    }
    __syncthreads();
    if (k0 > row) continue;   // fully masked for this thread (loads still done)

#pragma unroll 1
    for (int sub = 0; sub < 4; ++sub) {
      const int kb = k0 + (sub << 4);
      if (kb > row) break;

      float s[16];
#pragma unroll
      for (int kk = 0; kk < 16; ++kk) {
        const int key = (sub << 4) + kk;
        float acc = 0.f;
#pragma unroll
        for (int d4 = 0; d4 < 16; ++d4) {
          const float4 kv = *reinterpret_cast<const float4*>(&Ks[key][d4 << 2]);
          acc = fmaf(q[(d4<<2)+0], kv.x, acc);
          acc = fmaf(q[(d4<<2)+1], kv.y, acc);
          acc = fmaf(q[(d4<<2)+2], kv.z, acc);
          acc = fmaf(q[(d4<<2)+3], kv.w, acc);
        }
        s[kk] = (kb + kk <= row) ? acc * ATT_SCALE : -INFINITY;
      }

      float smax = -INFINITY;
#pragma unroll
      for (int kk = 0; kk < 16; ++kk) smax = fmaxf(smax, s[kk]);
      const float newm  = fmaxf(m, smax);           // finite: key kb <= row is live
      const float scale = __expf(m - newm);
#pragma unroll
      for (int d = 0; d < DH; ++d) o[d] *= scale;

      float psum = 0.f;
#pragma unroll
      for (int kk = 0; kk < 16; ++kk) {
        const float p = __expf(s[kk] - newm);
        psum += p;
        const int key = (sub << 4) + kk;
#pragma unroll
        for (int d4 = 0; d4 < 16; ++d4) {
          const float4 vv = *reinterpret_cast<const float4*>(&Vs[key][d4 << 2]);
          o[(d4<<2)+0] = fmaf(p, vv.x, o[(d4<<2)+0]);
          o[(d4<<2)+1] = fmaf(p, vv.y, o[(d4<<2)+1]);
          o[(d4<<2)+2] = fmaf(p, vv.z, o[(d4<<2)+2]);
          o[(d4<<2)+3] = fmaf(p, vv.w, o[(d4<<2)+3]);
        }
      }
      l = l * scale + psum;
      m = newm;
    }
  }

  const float inv = 1.0f / l;
  const int b = bh >> 4, h = bh & 15;
  float* Orow = Op + ((size_t)b * S_LEN + row) * DE + h * DH;
#pragma unroll
  for (int d4 = 0; d4 < 16; ++d4) {
    const float4 v = make_float4(o[(d4<<2)+0] * inv, o[(d4<<2)+1] * inv,
                                 o[(d4<<2)+2] * inv, o[(d4<<2)+3] * inv);
    *reinterpret_cast<float4*>(Orow + (d4 << 2)) = v;
  }
}

}  // namespace

extern "C" void kernel_launch(void* const* d_in, const int* in_sizes, int n_in,
                              void* d_out, int out_size, void* d_ws, size_t ws_size,
                              hipStream_t stream) {
  const float* x  = (const float*)d_in[0];
  const float* Wq = (const float*)d_in[1];
  const float* Wk = (const float*)d_in[2];
  const float* Wv = (const float*)d_in[3];
  const float* Wo = (const float*)d_in[4];
  float* out = (float*)d_out;

  float* ws = (float*)d_ws;
  const size_t per = (size_t)2 * NH * S_LEN * DH;  // 4,194,304 floats per tensor
  const size_t need_bytes = 4 * per * sizeof(float);  // Q,K,V,O = 64 MiB

  // Guard: if the harness workspace is too small, do NOT scribble past it
  // (that would kill the container). A clean validation failure next round
  // would tell us ws_size is the constraint.
  if (ws_size < need_bytes) return;

  float* Qw = ws;
  float* Kw = ws + per;
  float* Vw = ws + 2 * per;
  float* Ow = ws + 3 * per;

  const int M = 2 * S_LEN;  // 4096 token rows
  dim3 gg(M / 64, DE / 64);
  dim3 bb(256);

  gemm_nt_kernel<<<gg, bb, 0, stream>>>(x, Wq, Qw, M, DE, DE, 1);
  gemm_nt_kernel<<<gg, bb, 0, stream>>>(x, Wk, Kw, M, DE, DE, 1);
  gemm_nt_kernel<<<gg, bb, 0, stream>>>(x, Wv, Vw, M, DE, DE, 1);

  attn_kernel<<<dim3(2 * NH, S_LEN / 256), bb, 0, stream>>>(Qw, Kw, Vw, Ow);

  gemm_nt_kernel<<<gg, bb, 0, stream>>>(Ow, Wo, out, M, DE, DE, 0);
}